// Round 1
// baseline (1108.039 us; speedup 1.0000x reference)
//
#include <hip/hip_runtime.h>
#include <stdint.h>

#define NUM_CLASSES 80
#define N_ANCH 25200
#define B_IMG 16
#define NMS_TOPK_ 128
#define MAX_OUT_ 100
#define SCORE_THR_ 0.25f
#define IOU_THR_ 0.45f
#define NBINS 2048
#define CAP 2048

__constant__ float c_anch[9][2] = {
    {10.f, 13.f}, {16.f, 30.f}, {33.f, 23.f},
    {30.f, 61.f}, {62.f, 45.f}, {59.f, 119.f},
    {116.f, 90.f}, {156.f, 198.f}, {373.f, 326.f}};

__device__ __forceinline__ float sigmoidf_(float x) {
    return 1.0f / (1.0f + expf(-x));
}

// ---------------- Stage A: decode boxes + sigmoid(obj) ----------------
__global__ void __launch_bounds__(256) decode_kernel(
    const float* __restrict__ p3, const float* __restrict__ p4,
    const float* __restrict__ p5, float* __restrict__ boxes,
    float* __restrict__ obj) {
    int gid = blockIdx.x * blockDim.x + threadIdx.x;
    if (gid >= B_IMG * N_ANCH) return;
    int b = gid / N_ANCH;
    int i = gid - b * N_ANCH;
    const float* p; int W, il, lvl; float stride;
    if (i < 19200)      { p = p3; W = 80; il = i;         lvl = 0; stride = 8.f;  }
    else if (i < 24000) { p = p4; W = 40; il = i - 19200; lvl = 1; stride = 16.f; }
    else                { p = p5; W = 20; il = i - 24000; lvl = 2; stride = 32.f; }
    int y = il / (W * 3);
    int t = il - y * W * 3;
    int x = t / 3;
    int a = t - x * 3;
    const float* q = p + ((((size_t)b * W + y) * W + x) * 255 + a * 85);
    float tx = q[0], ty = q[1], tw = q[2], th = q[3], to = q[4];
    float cx = (sigmoidf_(tx) + (float)x) * stride;
    float cy = (sigmoidf_(ty) + (float)y) * stride;
    float bw = expf(tw) * c_anch[lvl * 3 + a][0];
    float bh = expf(th) * c_anch[lvl * 3 + a][1];
    float* bo = boxes + (size_t)gid * 4;
    bo[0] = cx - bw * 0.5f;
    bo[1] = cy - bh * 0.5f;
    bo[2] = cx + bw * 0.5f;
    bo[3] = cy + bh * 0.5f;
    obj[gid] = sigmoidf_(to);
}

__device__ __forceinline__ float cand_score(
    const float* __restrict__ p3, const float* __restrict__ p4,
    const float* __restrict__ p5, const float* __restrict__ obj,
    int b, int c, int i) {
    const float* p; int W, il;
    if (i < 19200)      { p = p3; W = 80; il = i;         }
    else if (i < 24000) { p = p4; W = 40; il = i - 19200; }
    else                { p = p5; W = 20; il = i - 24000; }
    int y = il / (W * 3);
    int t = il - y * W * 3;
    int x = t / 3;
    int a = t - x * 3;
    float cl = p[(((size_t)b * W + y) * W + x) * 255 + a * 85 + 5 + c];
    return obj[b * N_ANCH + i] * sigmoidf_(cl);
}

// ------------- Stage B: per (image,class) top-128 + NMS + first-100 -------------
__global__ void __launch_bounds__(256) topk_nms_kernel(
    const float* __restrict__ p3, const float* __restrict__ p4,
    const float* __restrict__ p5, const float* __restrict__ boxes,
    const float* __restrict__ obj, float* __restrict__ cls_score,
    float* __restrict__ cls_box) {
    int b = blockIdx.x / NUM_CLASSES;
    int c = blockIdx.x % NUM_CLASSES;
    int tid = threadIdx.x;

    __shared__ unsigned int hist[NBINS];
    __shared__ unsigned long long keys[CAP];
    __shared__ unsigned int s_cnt, s_cutoff;
    __shared__ float bx[NMS_TOPK_][4];
    __shared__ float bs[NMS_TOPK_];
    __shared__ int keep[NMS_TOPK_];

    for (int k = tid; k < NBINS; k += 256) hist[k] = 0u;
    if (tid == 0) s_cnt = 0u;
    __syncthreads();

    // Pass 1: histogram of score bits (monotonic for scores in (0.25,1))
    for (int i = tid; i < N_ANCH; i += 256) {
        float s = cand_score(p3, p4, p5, obj, b, c, i);
        if (s > SCORE_THR_) {
            unsigned int bits = __float_as_uint(s);
            unsigned int bin = (bits - 0x3E800000u) >> 13;
            if (bin >= NBINS) bin = NBINS - 1;
            atomicAdd(&hist[bin], 1u);
        }
    }
    __syncthreads();

    if (tid == 0) {
        unsigned int total = 0;
        int cut = 0;
        for (int k = NBINS - 1; k >= 0; --k) {
            total += hist[k];
            if (total >= NMS_TOPK_) { cut = k; break; }
        }
        s_cutoff = (unsigned int)cut;
    }
    __syncthreads();
    unsigned int cutoff = s_cutoff;

    // Pass 2: collect candidates at/above the cutoff bin
    for (int i = tid; i < N_ANCH; i += 256) {
        float s = cand_score(p3, p4, p5, obj, b, c, i);
        if (s > SCORE_THR_) {
            unsigned int bits = __float_as_uint(s);
            unsigned int bin = (bits - 0x3E800000u) >> 13;
            if (bin >= NBINS) bin = NBINS - 1;
            if (bin >= cutoff) {
                unsigned int pos = atomicAdd(&s_cnt, 1u);
                if (pos < CAP) {
                    keys[pos] = ((unsigned long long)bits << 32) |
                                (unsigned long long)(~(unsigned int)i);
                }
            }
        }
    }
    __syncthreads();

    unsigned int M = s_cnt;
    if (M > CAP) M = CAP;
    unsigned int P2 = 1;
    while (P2 < M) P2 <<= 1;
    if (P2 < 2) P2 = 2;
    for (unsigned int k = M + tid; k < P2; k += 256) keys[k] = 0ull;
    __syncthreads();

    // Bitonic sort, descending (score desc, then index asc via ~idx)
    for (unsigned int k = 2; k <= P2; k <<= 1) {
        for (unsigned int j = k >> 1; j > 0; j >>= 1) {
            for (unsigned int t = tid; t < P2; t += 256) {
                unsigned int ixj = t ^ j;
                if (ixj > t) {
                    unsigned long long a0 = keys[t], b0 = keys[ixj];
                    bool desc = ((t & k) == 0);
                    if (desc ? (a0 < b0) : (a0 > b0)) {
                        keys[t] = b0;
                        keys[ixj] = a0;
                    }
                }
            }
            __syncthreads();
        }
    }

    unsigned int K = M < NMS_TOPK_ ? M : NMS_TOPK_;
    if (tid < (int)K) {
        unsigned long long kk = keys[tid];
        unsigned int idx = ~((unsigned int)(kk & 0xFFFFFFFFull));
        const float* bp = boxes + ((size_t)b * N_ANCH + idx) * 4;
        bx[tid][0] = bp[0]; bx[tid][1] = bp[1];
        bx[tid][2] = bp[2]; bx[tid][3] = bp[3];
        bs[tid] = __uint_as_float((unsigned int)(kk >> 32));
        keep[tid] = 1;
    }
    __syncthreads();

    // Greedy NMS, exact reference scan semantics
    for (unsigned int i = 0; i < K; ++i) {
        if (keep[i]) {  // bs[i] > 0 always (score > 0.25)
            unsigned int t = (unsigned int)tid;
            if (t > i && t < K && keep[t]) {
                float ax0 = bx[i][0], ay0 = bx[i][1], ax1 = bx[i][2], ay1 = bx[i][3];
                float cx0 = bx[t][0], cy0 = bx[t][1], cx1 = bx[t][2], cy1 = bx[t][3];
                float areaA = (ax1 - ax0) * (ay1 - ay0);
                float areaB = (cx1 - cx0) * (cy1 - cy0);
                float lx = fmaxf(ax0, cx0), ly = fmaxf(ay0, cy0);
                float rx = fminf(ax1, cx1), ry = fminf(ay1, cy1);
                float w = rx - lx; if (w < 0.f) w = 0.f;
                float h = ry - ly; if (h < 0.f) h = 0.f;
                float inter = w * h;
                float iou = inter / (areaA + areaB - inter + 1e-9f);
                if (iou > IOU_THR_) keep[t] = 0;
            }
        }
        __syncthreads();
    }

    // Compact: first 100 survivors in sorted order; pad with score=-1
    if (tid == 0) {
        float* sc = cls_score + ((size_t)b * NUM_CLASSES + c) * MAX_OUT_;
        float* bo = cls_box + ((size_t)b * NUM_CLASSES + c) * MAX_OUT_ * 4;
        int out_n = 0;
        for (unsigned int t2 = 0; t2 < K && out_n < MAX_OUT_; ++t2) {
            if (keep[t2]) {
                sc[out_n] = bs[t2];
                bo[out_n * 4 + 0] = bx[t2][0];
                bo[out_n * 4 + 1] = bx[t2][1];
                bo[out_n * 4 + 2] = bx[t2][2];
                bo[out_n * 4 + 3] = bx[t2][3];
                out_n++;
            }
        }
        for (; out_n < MAX_OUT_; ++out_n) {
            sc[out_n] = -1.0f;
            bo[out_n * 4 + 0] = 0.f; bo[out_n * 4 + 1] = 0.f;
            bo[out_n * 4 + 2] = 0.f; bo[out_n * 4 + 3] = 0.f;
        }
    }
}

// ------------- Stage C: per-image final top-100 across classes -------------
__global__ void __launch_bounds__(256) final_topk_kernel(
    const float* __restrict__ cls_score, const float* __restrict__ cls_box,
    float* __restrict__ out) {
    int b = blockIdx.x;
    int tid = threadIdx.x;
    const int NC = NUM_CLASSES * MAX_OUT_;  // 8000

    __shared__ float sc[NUM_CLASSES * MAX_OUT_];
    __shared__ float rv[256];
    __shared__ int ri[256];
    __shared__ int s_count;

    for (int k = tid; k < NC; k += 256) sc[k] = cls_score[(size_t)b * NC + k];
    if (tid == 0) s_count = 0;
    __syncthreads();

    float* ob = out;                               // boxes  16*100*4
    float* os = out + B_IMG * MAX_OUT_ * 4;        // scores 16*100
    float* oc = os + B_IMG * MAX_OUT_;             // cls    16*100
    float* on = oc + B_IMG * MAX_OUT_;             // n_valid 16

    for (int k = 0; k < MAX_OUT_; ++k) {
        float bv = -1e30f; int bi = NC - 1;
        for (int t = tid; t < NC; t += 256) {
            float v = sc[t];
            if (v > bv || (v == bv && t < bi)) { bv = v; bi = t; }
        }
        rv[tid] = bv; ri[tid] = bi;
        __syncthreads();
        for (int off = 128; off > 0; off >>= 1) {
            if (tid < off) {
                float v2 = rv[tid + off]; int i2 = ri[tid + off];
                if (v2 > rv[tid] || (v2 == rv[tid] && i2 < ri[tid])) {
                    rv[tid] = v2; ri[tid] = i2;
                }
            }
            __syncthreads();
        }
        if (tid == 0) {
            float sel_v = rv[0]; int sel_i = ri[0];
            bool valid = sel_v > 0.0f;
            if (valid) s_count++;
            os[b * MAX_OUT_ + k] = valid ? sel_v : 0.0f;
            oc[b * MAX_OUT_ + k] = valid ? (float)(sel_i / MAX_OUT_) : 0.0f;
            const float* bp = cls_box + ((size_t)b * NC + sel_i) * 4;
            ob[(b * MAX_OUT_ + k) * 4 + 0] = valid ? bp[0] : 0.0f;
            ob[(b * MAX_OUT_ + k) * 4 + 1] = valid ? bp[1] : 0.0f;
            ob[(b * MAX_OUT_ + k) * 4 + 2] = valid ? bp[2] : 0.0f;
            ob[(b * MAX_OUT_ + k) * 4 + 3] = valid ? bp[3] : 0.0f;
            sc[sel_i] = -2.0f;  // exclude from later iterations
        }
        __syncthreads();
    }
    if (tid == 0) on[b] = (float)s_count;
}

extern "C" void kernel_launch(void* const* d_in, const int* in_sizes, int n_in,
                              void* d_out, int out_size, void* d_ws, size_t ws_size,
                              hipStream_t stream) {
    const float* p3 = (const float*)d_in[0];
    const float* p4 = (const float*)d_in[1];
    const float* p5 = (const float*)d_in[2];

    float* ws = (float*)d_ws;
    float* boxes = ws;                                   // 16*25200*4
    float* obj = boxes + (size_t)B_IMG * N_ANCH * 4;     // 16*25200
    float* cls_score = obj + (size_t)B_IMG * N_ANCH;     // 16*8000
    float* cls_box = cls_score + (size_t)B_IMG * NUM_CLASSES * MAX_OUT_;  // 16*8000*4

    int tot = B_IMG * N_ANCH;
    decode_kernel<<<(tot + 255) / 256, 256, 0, stream>>>(p3, p4, p5, boxes, obj);
    topk_nms_kernel<<<B_IMG * NUM_CLASSES, 256, 0, stream>>>(
        p3, p4, p5, boxes, obj, cls_score, cls_box);
    final_topk_kernel<<<B_IMG, 256, 0, stream>>>(cls_score, cls_box, (float*)d_out);
}

// Round 2
// 348.759 us; speedup vs baseline: 3.1771x; 3.1771x over previous
//
#include <hip/hip_runtime.h>
#include <stdint.h>

#define NUM_CLASSES 80
#define N_ANCH 25200
#define B_IMG 16
#define NMS_TOPK_ 128
#define MAX_OUT_ 100
#define SCORE_THR_ 0.25f
#define IOU_THR_ 0.45f
#define NBINS 2048
#define CAP 2048      // fallback path capacity
#define CAPB 512      // fast stage-B capacity
#define CAPC 256      // fast stage-C capacity

__constant__ float c_anch[9][2] = {
    {10.f, 13.f}, {16.f, 30.f}, {33.f, 23.f},
    {30.f, 61.f}, {62.f, 45.f}, {59.f, 119.f},
    {116.f, 90.f}, {156.f, 198.f}, {373.f, 326.f}};

__device__ __forceinline__ float sigmoidf_(float x) {
    return 1.0f / (1.0f + expf(-x));
}

__device__ __forceinline__ unsigned int score_bin(unsigned int bits) {
    // scores in (0.25, 1.0): bits in (0x3E800000, 0x3F800000)
    unsigned int bin = (bits - 0x3E800000u) >> 13;
    if (bin >= NBINS) bin = NBINS - 1;
    return bin;
}

// ============================================================================
// FAST PATH
// ============================================================================

// ---- F1: decode boxes + write transposed scores score_t[b][c][anchor] ----
// Tiles of 48 anchors (48 divides 19200/4800/1200). 525 tiles/image.
__global__ void __launch_bounds__(256) decode_scores_kernel(
    const float* __restrict__ p3, const float* __restrict__ p4,
    const float* __restrict__ p5, float* __restrict__ boxes,
    float* __restrict__ score_t) {
    int blk = blockIdx.x;
    int b = blk / 525;
    int tile = blk - b * 525;
    const float* p; int W, lvl, il0, base;
    if (tile < 400)      { p = p3; W = 80; lvl = 0; il0 = tile * 48;         base = 0;     }
    else if (tile < 500) { p = p4; W = 40; lvl = 1; il0 = (tile - 400) * 48; base = 19200; }
    else                 { p = p5; W = 20; lvl = 2; il0 = (tile - 500) * 48; base = 24000; }
    float stride = (float)(8 << lvl);
    const float* src = p + (size_t)b * ((size_t)W * W * 255) + (size_t)il0 * 85;

    __shared__ float raw[48 * 85];
    __shared__ float obj_sh[48];
    int tid = threadIdx.x;

    for (int k = tid; k < 48 * 85; k += 256) raw[k] = src[k];
    __syncthreads();

    if (tid < 48) {
        int il = il0 + tid;
        int y = il / (W * 3);
        int t = il - y * (W * 3);
        int x = t / 3;
        int a = t - x * 3;
        const float* q = &raw[tid * 85];
        float cx = (sigmoidf_(q[0]) + (float)x) * stride;
        float cy = (sigmoidf_(q[1]) + (float)y) * stride;
        float bw = expf(q[2]) * c_anch[lvl * 3 + a][0];
        float bh = expf(q[3]) * c_anch[lvl * 3 + a][1];
        int gi = base + il;
        float* bo = boxes + ((size_t)b * N_ANCH + gi) * 4;
        bo[0] = cx - bw * 0.5f; bo[1] = cy - bh * 0.5f;
        bo[2] = cx + bw * 0.5f; bo[3] = cy + bh * 0.5f;
        obj_sh[tid] = sigmoidf_(q[4]);
    }
    __syncthreads();

    int gi0 = base + il0;
    for (int o = tid; o < NUM_CLASSES * 48; o += 256) {
        int c = o / 48;
        int j = o - c * 48;
        float s = obj_sh[j] * sigmoidf_(raw[j * 85 + 5 + c]);
        score_t[((size_t)(b * NUM_CLASSES + c)) * N_ANCH + gi0 + j] = s;
    }
}

// ---- F2: per (image,class) top-128 (histogram cutoff) + NMS ----
__global__ void __launch_bounds__(256) topk_nms_fast_kernel(
    const float* __restrict__ score_t, const float* __restrict__ boxes,
    float* __restrict__ cls_score, float* __restrict__ cls_box) {
    int b = blockIdx.x / NUM_CLASSES;
    int c = blockIdx.x % NUM_CLASSES;
    int tid = threadIdx.x;
    const float* sc = score_t + (size_t)(b * NUM_CLASSES + c) * N_ANCH;
    const float4* sc4 = (const float4*)sc;

    __shared__ unsigned int hist[NBINS];
    __shared__ unsigned int segsum[256];
    __shared__ unsigned long long keys[CAPB];
    __shared__ unsigned int s_cnt;
    __shared__ int s_cut;
    __shared__ float bx[NMS_TOPK_][5];   // +1 pad: kills stride-4 bank conflicts
    __shared__ float bs[NMS_TOPK_];
    __shared__ int keep[NMS_TOPK_];

    for (int k = tid; k < NBINS; k += 256) hist[k] = 0u;
    if (tid == 0) s_cnt = 0u;
    __syncthreads();

    // Pass 1: histogram (coalesced float4 reads)
    for (int i = tid; i < N_ANCH / 4; i += 256) {
        float4 v = sc4[i];
        float vv[4] = {v.x, v.y, v.z, v.w};
#pragma unroll
        for (int k = 0; k < 4; ++k) {
            if (vv[k] > SCORE_THR_)
                atomicAdd(&hist[score_bin(__float_as_uint(vv[k]))], 1u);
        }
    }
    __syncthreads();

    // Parallel-ish cutoff for rank 128
    unsigned int ss = 0;
    for (int k = 0; k < 8; ++k) ss += hist[tid * 8 + k];
    segsum[tid] = ss;
    __syncthreads();
    if (tid == 0) {
        unsigned int tot = 0; int cut = 0; int t = 255;
        for (; t >= 0; --t) {
            if (tot + segsum[t] >= NMS_TOPK_) break;
            tot += segsum[t];
        }
        if (t >= 0) {
            int j = 7;
            for (; j >= 0; --j) { tot += hist[t * 8 + j]; if (tot >= NMS_TOPK_) break; }
            if (j < 0) j = 0;
            cut = t * 8 + j;
        }
        s_cut = cut;
    }
    __syncthreads();
    unsigned int cutoff = (unsigned int)s_cut;

    // Pass 2: collect candidates at/above cutoff bin
    for (int i = tid; i < N_ANCH / 4; i += 256) {
        float4 v = sc4[i];
        float vv[4] = {v.x, v.y, v.z, v.w};
#pragma unroll
        for (int k = 0; k < 4; ++k) {
            if (vv[k] > SCORE_THR_) {
                unsigned int bits = __float_as_uint(vv[k]);
                if (score_bin(bits) >= cutoff) {
                    unsigned int pos = atomicAdd(&s_cnt, 1u);
                    if (pos < CAPB) {
                        keys[pos] = ((unsigned long long)bits << 32) |
                                    (unsigned long long)(~(unsigned int)(i * 4 + k));
                    }
                }
            }
        }
    }
    __syncthreads();

    unsigned int M = s_cnt;
    if (M > CAPB) M = CAPB;
    unsigned int P2 = 1;
    while (P2 < M) P2 <<= 1;
    if (P2 < 2) P2 = 2;
    for (unsigned int k = M + tid; k < P2; k += 256) keys[k] = 0ull;
    __syncthreads();

    // Bitonic sort descending (score desc, index asc via ~idx)
    for (unsigned int k = 2; k <= P2; k <<= 1) {
        for (unsigned int j = k >> 1; j > 0; j >>= 1) {
            for (unsigned int t = tid; t < P2; t += 256) {
                unsigned int ixj = t ^ j;
                if (ixj > t) {
                    unsigned long long a0 = keys[t], b0 = keys[ixj];
                    bool desc = ((t & k) == 0);
                    if (desc ? (a0 < b0) : (a0 > b0)) { keys[t] = b0; keys[ixj] = a0; }
                }
            }
            __syncthreads();
        }
    }

    unsigned int K = M < NMS_TOPK_ ? M : NMS_TOPK_;
    if (tid < (int)K) {
        unsigned long long kk = keys[tid];
        unsigned int idx = ~((unsigned int)(kk & 0xFFFFFFFFull));
        const float* bp = boxes + ((size_t)b * N_ANCH + idx) * 4;
        bx[tid][0] = bp[0]; bx[tid][1] = bp[1];
        bx[tid][2] = bp[2]; bx[tid][3] = bp[3];
        bs[tid] = __uint_as_float((unsigned int)(kk >> 32));
        keep[tid] = 1;
    }
    __syncthreads();

    // Greedy NMS, exact reference scan semantics
    for (unsigned int i = 0; i < K; ++i) {
        if (keep[i]) {
            unsigned int t = (unsigned int)tid;
            if (t > i && t < K && keep[t]) {
                float ax0 = bx[i][0], ay0 = bx[i][1], ax1 = bx[i][2], ay1 = bx[i][3];
                float cx0 = bx[t][0], cy0 = bx[t][1], cx1 = bx[t][2], cy1 = bx[t][3];
                float areaA = (ax1 - ax0) * (ay1 - ay0);
                float areaB = (cx1 - cx0) * (cy1 - cy0);
                float lx = fmaxf(ax0, cx0), ly = fmaxf(ay0, cy0);
                float rx = fminf(ax1, cx1), ry = fminf(ay1, cy1);
                float w = rx - lx; if (w < 0.f) w = 0.f;
                float h = ry - ly; if (h < 0.f) h = 0.f;
                float inter = w * h;
                float iou = inter / (areaA + areaB - inter + 1e-9f);
                if (iou > IOU_THR_) keep[t] = 0;
            }
        }
        __syncthreads();
    }

    if (tid == 0) {
        float* scd = cls_score + ((size_t)b * NUM_CLASSES + c) * MAX_OUT_;
        float* bod = cls_box + ((size_t)b * NUM_CLASSES + c) * MAX_OUT_ * 4;
        int out_n = 0;
        for (unsigned int t2 = 0; t2 < K && out_n < MAX_OUT_; ++t2) {
            if (keep[t2]) {
                scd[out_n] = bs[t2];
                bod[out_n * 4 + 0] = bx[t2][0];
                bod[out_n * 4 + 1] = bx[t2][1];
                bod[out_n * 4 + 2] = bx[t2][2];
                bod[out_n * 4 + 3] = bx[t2][3];
                out_n++;
            }
        }
        for (; out_n < MAX_OUT_; ++out_n) {
            scd[out_n] = -1.0f;
            bod[out_n * 4 + 0] = 0.f; bod[out_n * 4 + 1] = 0.f;
            bod[out_n * 4 + 2] = 0.f; bod[out_n * 4 + 3] = 0.f;
        }
    }
}

// ---- F3: per-image final top-100 via histogram cutoff ----
__global__ void __launch_bounds__(256) final_fast_kernel(
    const float* __restrict__ cls_score, const float* __restrict__ cls_box,
    float* __restrict__ out) {
    int b = blockIdx.x;
    int tid = threadIdx.x;
    const int NC = NUM_CLASSES * MAX_OUT_;  // 8000
    const float* sc = cls_score + (size_t)b * NC;

    __shared__ unsigned int hist[NBINS];
    __shared__ unsigned int segsum[256];
    __shared__ unsigned long long keys[CAPC];
    __shared__ unsigned int s_cnt, s_tot;
    __shared__ int s_cut;

    for (int k = tid; k < NBINS; k += 256) hist[k] = 0u;
    if (tid == 0) s_cnt = 0u;
    __syncthreads();

    // all valid entries are > 0.25; invalid are -1
    for (int k = tid; k < NC; k += 256) {
        float s = sc[k];
        if (s > 0.0f) atomicAdd(&hist[score_bin(__float_as_uint(s))], 1u);
    }
    __syncthreads();

    unsigned int ss = 0;
    for (int k = 0; k < 8; ++k) ss += hist[tid * 8 + k];
    segsum[tid] = ss;
    __syncthreads();
    if (tid == 0) {
        unsigned int total = 0;
        for (int t = 0; t < 256; ++t) total += segsum[t];
        s_tot = total;
        unsigned int tot = 0; int cut = 0; int t = 255;
        for (; t >= 0; --t) {
            if (tot + segsum[t] >= MAX_OUT_) break;
            tot += segsum[t];
        }
        if (t >= 0) {
            int j = 7;
            for (; j >= 0; --j) { tot += hist[t * 8 + j]; if (tot >= MAX_OUT_) break; }
            if (j < 0) j = 0;
            cut = t * 8 + j;
        }
        s_cut = cut;
    }
    __syncthreads();
    unsigned int cutoff = (unsigned int)s_cut;

    for (int k = tid; k < NC; k += 256) {
        float s = sc[k];
        if (s > 0.0f && score_bin(__float_as_uint(s)) >= cutoff) {
            unsigned int pos = atomicAdd(&s_cnt, 1u);
            if (pos < CAPC) {
                keys[pos] = ((unsigned long long)__float_as_uint(s) << 32) |
                            (unsigned long long)(~(unsigned int)k);
            }
        }
    }
    __syncthreads();

    unsigned int M = s_cnt;
    if (M > CAPC) M = CAPC;
    unsigned int P2 = 1;
    while (P2 < M) P2 <<= 1;
    if (P2 < 2) P2 = 2;
    for (unsigned int k = M + tid; k < P2; k += 256) keys[k] = 0ull;
    __syncthreads();

    for (unsigned int k = 2; k <= P2; k <<= 1) {
        for (unsigned int j = k >> 1; j > 0; j >>= 1) {
            for (unsigned int t = tid; t < P2; t += 256) {
                unsigned int ixj = t ^ j;
                if (ixj > t) {
                    unsigned long long a0 = keys[t], b0 = keys[ixj];
                    bool desc = ((t & k) == 0);
                    if (desc ? (a0 < b0) : (a0 > b0)) { keys[t] = b0; keys[ixj] = a0; }
                }
            }
            __syncthreads();
        }
    }

    float* ob = out;                              // boxes  16*100*4
    float* os = out + B_IMG * MAX_OUT_ * 4;       // scores 16*100
    float* oc = os + B_IMG * MAX_OUT_;            // cls    16*100
    float* on = oc + B_IMG * MAX_OUT_;            // n_valid 16

    unsigned int K = M < MAX_OUT_ ? M : MAX_OUT_;
    if (tid < MAX_OUT_) {
        if ((unsigned int)tid < K) {
            unsigned long long kk = keys[tid];
            unsigned int flat = ~((unsigned int)(kk & 0xFFFFFFFFull));
            float sv = __uint_as_float((unsigned int)(kk >> 32));
            const float* bp = cls_box + ((size_t)b * NC + flat) * 4;
            os[b * MAX_OUT_ + tid] = sv;
            oc[b * MAX_OUT_ + tid] = (float)(flat / MAX_OUT_);
            ob[(b * MAX_OUT_ + tid) * 4 + 0] = bp[0];
            ob[(b * MAX_OUT_ + tid) * 4 + 1] = bp[1];
            ob[(b * MAX_OUT_ + tid) * 4 + 2] = bp[2];
            ob[(b * MAX_OUT_ + tid) * 4 + 3] = bp[3];
        } else {
            os[b * MAX_OUT_ + tid] = 0.0f;
            oc[b * MAX_OUT_ + tid] = 0.0f;
            ob[(b * MAX_OUT_ + tid) * 4 + 0] = 0.0f;
            ob[(b * MAX_OUT_ + tid) * 4 + 1] = 0.0f;
            ob[(b * MAX_OUT_ + tid) * 4 + 2] = 0.0f;
            ob[(b * MAX_OUT_ + tid) * 4 + 3] = 0.0f;
        }
    }
    if (tid == 0) {
        unsigned int nv = s_tot < MAX_OUT_ ? s_tot : MAX_OUT_;
        on[b] = (float)nv;
    }
}

// ============================================================================
// FALLBACK PATH (round-1, known-correct) — used when ws_size is too small
// ============================================================================

__global__ void __launch_bounds__(256) decode_kernel(
    const float* __restrict__ p3, const float* __restrict__ p4,
    const float* __restrict__ p5, float* __restrict__ boxes,
    float* __restrict__ obj) {
    int gid = blockIdx.x * blockDim.x + threadIdx.x;
    if (gid >= B_IMG * N_ANCH) return;
    int b = gid / N_ANCH;
    int i = gid - b * N_ANCH;
    const float* p; int W, il, lvl; float stride;
    if (i < 19200)      { p = p3; W = 80; il = i;         lvl = 0; stride = 8.f;  }
    else if (i < 24000) { p = p4; W = 40; il = i - 19200; lvl = 1; stride = 16.f; }
    else                { p = p5; W = 20; il = i - 24000; lvl = 2; stride = 32.f; }
    int y = il / (W * 3);
    int t = il - y * W * 3;
    int x = t / 3;
    int a = t - x * 3;
    const float* q = p + ((((size_t)b * W + y) * W + x) * 255 + a * 85);
    float cx = (sigmoidf_(q[0]) + (float)x) * stride;
    float cy = (sigmoidf_(q[1]) + (float)y) * stride;
    float bw = expf(q[2]) * c_anch[lvl * 3 + a][0];
    float bh = expf(q[3]) * c_anch[lvl * 3 + a][1];
    float* bo = boxes + (size_t)gid * 4;
    bo[0] = cx - bw * 0.5f; bo[1] = cy - bh * 0.5f;
    bo[2] = cx + bw * 0.5f; bo[3] = cy + bh * 0.5f;
    obj[gid] = sigmoidf_(q[4]);
}

__device__ __forceinline__ float cand_score(
    const float* __restrict__ p3, const float* __restrict__ p4,
    const float* __restrict__ p5, const float* __restrict__ obj,
    int b, int c, int i) {
    const float* p; int W, il;
    if (i < 19200)      { p = p3; W = 80; il = i;         }
    else if (i < 24000) { p = p4; W = 40; il = i - 19200; }
    else                { p = p5; W = 20; il = i - 24000; }
    int y = il / (W * 3);
    int t = il - y * W * 3;
    int x = t / 3;
    int a = t - x * 3;
    float cl = p[(((size_t)b * W + y) * W + x) * 255 + a * 85 + 5 + c];
    return obj[b * N_ANCH + i] * sigmoidf_(cl);
}

__global__ void __launch_bounds__(256) topk_nms_kernel(
    const float* __restrict__ p3, const float* __restrict__ p4,
    const float* __restrict__ p5, const float* __restrict__ boxes,
    const float* __restrict__ obj, float* __restrict__ cls_score,
    float* __restrict__ cls_box) {
    int b = blockIdx.x / NUM_CLASSES;
    int c = blockIdx.x % NUM_CLASSES;
    int tid = threadIdx.x;

    __shared__ unsigned int hist[NBINS];
    __shared__ unsigned long long keys[CAP];
    __shared__ unsigned int s_cnt, s_cutoff;
    __shared__ float bx[NMS_TOPK_][5];
    __shared__ float bs[NMS_TOPK_];
    __shared__ int keep[NMS_TOPK_];

    for (int k = tid; k < NBINS; k += 256) hist[k] = 0u;
    if (tid == 0) s_cnt = 0u;
    __syncthreads();

    for (int i = tid; i < N_ANCH; i += 256) {
        float s = cand_score(p3, p4, p5, obj, b, c, i);
        if (s > SCORE_THR_) atomicAdd(&hist[score_bin(__float_as_uint(s))], 1u);
    }
    __syncthreads();

    if (tid == 0) {
        unsigned int total = 0;
        int cut = 0;
        for (int k = NBINS - 1; k >= 0; --k) {
            total += hist[k];
            if (total >= NMS_TOPK_) { cut = k; break; }
        }
        s_cutoff = (unsigned int)cut;
    }
    __syncthreads();
    unsigned int cutoff = s_cutoff;

    for (int i = tid; i < N_ANCH; i += 256) {
        float s = cand_score(p3, p4, p5, obj, b, c, i);
        if (s > SCORE_THR_) {
            unsigned int bits = __float_as_uint(s);
            if (score_bin(bits) >= cutoff) {
                unsigned int pos = atomicAdd(&s_cnt, 1u);
                if (pos < CAP) {
                    keys[pos] = ((unsigned long long)bits << 32) |
                                (unsigned long long)(~(unsigned int)i);
                }
            }
        }
    }
    __syncthreads();

    unsigned int M = s_cnt;
    if (M > CAP) M = CAP;
    unsigned int P2 = 1;
    while (P2 < M) P2 <<= 1;
    if (P2 < 2) P2 = 2;
    for (unsigned int k = M + tid; k < P2; k += 256) keys[k] = 0ull;
    __syncthreads();

    for (unsigned int k = 2; k <= P2; k <<= 1) {
        for (unsigned int j = k >> 1; j > 0; j >>= 1) {
            for (unsigned int t = tid; t < P2; t += 256) {
                unsigned int ixj = t ^ j;
                if (ixj > t) {
                    unsigned long long a0 = keys[t], b0 = keys[ixj];
                    bool desc = ((t & k) == 0);
                    if (desc ? (a0 < b0) : (a0 > b0)) { keys[t] = b0; keys[ixj] = a0; }
                }
            }
            __syncthreads();
        }
    }

    unsigned int K = M < NMS_TOPK_ ? M : NMS_TOPK_;
    if (tid < (int)K) {
        unsigned long long kk = keys[tid];
        unsigned int idx = ~((unsigned int)(kk & 0xFFFFFFFFull));
        const float* bp = boxes + ((size_t)b * N_ANCH + idx) * 4;
        bx[tid][0] = bp[0]; bx[tid][1] = bp[1];
        bx[tid][2] = bp[2]; bx[tid][3] = bp[3];
        bs[tid] = __uint_as_float((unsigned int)(kk >> 32));
        keep[tid] = 1;
    }
    __syncthreads();

    for (unsigned int i = 0; i < K; ++i) {
        if (keep[i]) {
            unsigned int t = (unsigned int)tid;
            if (t > i && t < K && keep[t]) {
                float ax0 = bx[i][0], ay0 = bx[i][1], ax1 = bx[i][2], ay1 = bx[i][3];
                float cx0 = bx[t][0], cy0 = bx[t][1], cx1 = bx[t][2], cy1 = bx[t][3];
                float areaA = (ax1 - ax0) * (ay1 - ay0);
                float areaB = (cx1 - cx0) * (cy1 - cy0);
                float lx = fmaxf(ax0, cx0), ly = fmaxf(ay0, cy0);
                float rx = fminf(ax1, cx1), ry = fminf(ay1, cy1);
                float w = rx - lx; if (w < 0.f) w = 0.f;
                float h = ry - ly; if (h < 0.f) h = 0.f;
                float inter = w * h;
                float iou = inter / (areaA + areaB - inter + 1e-9f);
                if (iou > IOU_THR_) keep[t] = 0;
            }
        }
        __syncthreads();
    }

    if (tid == 0) {
        float* scd = cls_score + ((size_t)b * NUM_CLASSES + c) * MAX_OUT_;
        float* bod = cls_box + ((size_t)b * NUM_CLASSES + c) * MAX_OUT_ * 4;
        int out_n = 0;
        for (unsigned int t2 = 0; t2 < K && out_n < MAX_OUT_; ++t2) {
            if (keep[t2]) {
                scd[out_n] = bs[t2];
                bod[out_n * 4 + 0] = bx[t2][0];
                bod[out_n * 4 + 1] = bx[t2][1];
                bod[out_n * 4 + 2] = bx[t2][2];
                bod[out_n * 4 + 3] = bx[t2][3];
                out_n++;
            }
        }
        for (; out_n < MAX_OUT_; ++out_n) {
            scd[out_n] = -1.0f;
            bod[out_n * 4 + 0] = 0.f; bod[out_n * 4 + 1] = 0.f;
            bod[out_n * 4 + 2] = 0.f; bod[out_n * 4 + 3] = 0.f;
        }
    }
}

extern "C" void kernel_launch(void* const* d_in, const int* in_sizes, int n_in,
                              void* d_out, int out_size, void* d_ws, size_t ws_size,
                              hipStream_t stream) {
    const float* p3 = (const float*)d_in[0];
    const float* p4 = (const float*)d_in[1];
    const float* p5 = (const float*)d_in[2];

    // Fast-path workspace layout
    const size_t score_t_elems = (size_t)B_IMG * NUM_CLASSES * N_ANCH;      // 32,256,000
    const size_t boxes_elems   = (size_t)B_IMG * N_ANCH * 4;                // 1,612,800
    const size_t clsS_elems    = (size_t)B_IMG * NUM_CLASSES * MAX_OUT_;    // 128,000
    const size_t clsB_elems    = clsS_elems * 4;                            // 512,000
    const size_t need_fast = (score_t_elems + boxes_elems + clsS_elems + clsB_elems) * sizeof(float);

    float* ws = (float*)d_ws;

    if (ws_size >= need_fast) {
        float* score_t  = ws;
        float* boxes    = score_t + score_t_elems;
        float* cls_score = boxes + boxes_elems;
        float* cls_box  = cls_score + clsS_elems;

        decode_scores_kernel<<<B_IMG * 525, 256, 0, stream>>>(p3, p4, p5, boxes, score_t);
        topk_nms_fast_kernel<<<B_IMG * NUM_CLASSES, 256, 0, stream>>>(
            score_t, boxes, cls_score, cls_box);
        final_fast_kernel<<<B_IMG, 256, 0, stream>>>(cls_score, cls_box, (float*)d_out);
    } else {
        // Fallback: round-1 path (~10 MB ws)
        float* boxes = ws;
        float* obj = boxes + boxes_elems;
        float* cls_score = obj + (size_t)B_IMG * N_ANCH;
        float* cls_box = cls_score + clsS_elems;

        int tot = B_IMG * N_ANCH;
        decode_kernel<<<(tot + 255) / 256, 256, 0, stream>>>(p3, p4, p5, boxes, obj);
        topk_nms_kernel<<<B_IMG * NUM_CLASSES, 256, 0, stream>>>(
            p3, p4, p5, boxes, obj, cls_score, cls_box);
        final_fast_kernel<<<B_IMG, 256, 0, stream>>>(cls_score, cls_box, (float*)d_out);
    }
}

// Round 3
// 336.461 us; speedup vs baseline: 3.2932x; 1.0366x over previous
//
#include <hip/hip_runtime.h>
#include <stdint.h>

#define NUM_CLASSES 80
#define N_ANCH 25200
#define B_IMG 16
#define NMS_TOPK_ 128
#define MAX_OUT_ 100
#define SCORE_THR_ 0.25f
#define IOU_THR_ 0.45f
#define NBINS 2048
#define CAP 2048      // fallback path capacity
#define CAPB 512      // fast stage-B candidate capacity
#define CAPC 256      // stage-C capacity
#define TILE_A 80     // anchors per decode block

__constant__ float c_anch[9][2] = {
    {10.f, 13.f}, {16.f, 30.f}, {33.f, 23.f},
    {30.f, 61.f}, {62.f, 45.f}, {59.f, 119.f},
    {116.f, 90.f}, {156.f, 198.f}, {373.f, 326.f}};

__device__ __forceinline__ float sigmoidf_(float x) {
    return 1.0f / (1.0f + expf(-x));
}

__device__ __forceinline__ unsigned int score_bin(unsigned int bits) {
    // scores in (0.25, 1.0): bits in (0x3E800000, 0x3F800000)
    unsigned int bin = (bits - 0x3E800000u) >> 13;
    if (bin >= NBINS) bin = NBINS - 1;
    return bin;
}

// ============================================================================
// FAST PATH
// ============================================================================

// ---- F1: decode boxes + write transposed scores score_t[b][c][anchor] ----
// 80-anchor tiles: p3=240, p4=60, p5=15 tiles/image -> 315; float4 loads/stores.
__global__ void __launch_bounds__(256) decode_scores_kernel(
    const float* __restrict__ p3, const float* __restrict__ p4,
    const float* __restrict__ p5, float* __restrict__ boxes,
    float* __restrict__ score_t) {
    int blk = blockIdx.x;
    int b = blk / 315;
    int tile = blk - b * 315;
    const float* p; int W, lvl, il0, base;
    if (tile < 240)      { p = p3; W = 80; lvl = 0; il0 = tile * TILE_A;         base = 0;     }
    else if (tile < 300) { p = p4; W = 40; lvl = 1; il0 = (tile - 240) * TILE_A; base = 19200; }
    else                 { p = p5; W = 20; lvl = 2; il0 = (tile - 300) * TILE_A; base = 24000; }
    float stride = (float)(8 << lvl);

    __shared__ float4 raw4[TILE_A * 85 / 4];   // 27200 B
    __shared__ float obj_sh[TILE_A];
    float* raw = (float*)raw4;
    int tid = threadIdx.x;

    const float4* src4 = (const float4*)(p + (size_t)b * ((size_t)W * W * 255) +
                                         (size_t)il0 * 85);
    for (int k = tid; k < TILE_A * 85 / 4; k += 256) raw4[k] = src4[k];
    __syncthreads();

    if (tid < TILE_A) {
        int il = il0 + tid;
        int y = il / (W * 3);
        int t = il - y * (W * 3);
        int x = t / 3;
        int a = t - x * 3;
        const float* q = &raw[tid * 85];
        float cx = (sigmoidf_(q[0]) + (float)x) * stride;
        float cy = (sigmoidf_(q[1]) + (float)y) * stride;
        float bw = expf(q[2]) * c_anch[lvl * 3 + a][0];
        float bh = expf(q[3]) * c_anch[lvl * 3 + a][1];
        int gi = base + il;
        float* bo = boxes + ((size_t)b * N_ANCH + gi) * 4;
        bo[0] = cx - bw * 0.5f; bo[1] = cy - bh * 0.5f;
        bo[2] = cx + bw * 0.5f; bo[3] = cy + bh * 0.5f;
        obj_sh[tid] = sigmoidf_(q[4]);
    }
    __syncthreads();

    int gi0 = base + il0;
    // 80 classes x 20 float4 anchors = 1600 vector stores
    for (int o = tid; o < NUM_CLASSES * (TILE_A / 4); o += 256) {
        int c = o / (TILE_A / 4);
        int q = o - c * (TILE_A / 4);
        int j = q * 4;
        float4 v;
        v.x = obj_sh[j + 0] * sigmoidf_(raw[(j + 0) * 85 + 5 + c]);
        v.y = obj_sh[j + 1] * sigmoidf_(raw[(j + 1) * 85 + 5 + c]);
        v.z = obj_sh[j + 2] * sigmoidf_(raw[(j + 2) * 85 + 5 + c]);
        v.w = obj_sh[j + 3] * sigmoidf_(raw[(j + 3) * 85 + 5 + c]);
        float4* dst = (float4*)(score_t + ((size_t)(b * NUM_CLASSES + c)) * N_ANCH + gi0);
        dst[q] = v;
    }
}

// ---- F2: per (image,class) top-128 + NMS, barrier-light ----
__global__ void __launch_bounds__(256) topk_nms_fast_kernel(
    const float* __restrict__ score_t, const float* __restrict__ boxes,
    float* __restrict__ cls_score, float* __restrict__ cls_box) {
    int b = blockIdx.x / NUM_CLASSES;
    int c = blockIdx.x % NUM_CLASSES;
    int tid = threadIdx.x;
    int lane = tid & 63;
    int wave = tid >> 6;
    const float4* sc4 = (const float4*)(score_t + (size_t)(b * NUM_CLASSES + c) * N_ANCH);

    __shared__ unsigned int hist[NBINS];          // 8 KB
    __shared__ unsigned int segsum[256];          // 1 KB
    __shared__ unsigned long long sel[CAPB];      // 4 KB
    __shared__ float bx[NMS_TOPK_][5];            // box(4) + score(1); pad kills conflicts
    __shared__ unsigned int s_cnt;
    __shared__ int s_cut;

    for (int k = tid; k < NBINS; k += 256) hist[k] = 0u;
    if (tid == 0) s_cnt = 0u;
    __syncthreads();

    // Pass 1: histogram (coalesced float4 reads)
    for (int i = tid; i < N_ANCH / 4; i += 256) {
        float4 v = sc4[i];
        float vv[4] = {v.x, v.y, v.z, v.w};
#pragma unroll
        for (int k = 0; k < 4; ++k) {
            if (vv[k] > SCORE_THR_)
                atomicAdd(&hist[score_bin(__float_as_uint(vv[k]))], 1u);
        }
    }
    __syncthreads();

    // cutoff for rank 128
    unsigned int ss = 0;
    for (int k = 0; k < 8; ++k) ss += hist[tid * 8 + k];
    segsum[tid] = ss;
    __syncthreads();
    if (tid == 0) {
        unsigned int tot = 0; int cut = 0; int t = 255;
        for (; t >= 0; --t) {
            if (tot + segsum[t] >= NMS_TOPK_) break;
            tot += segsum[t];
        }
        if (t >= 0) {
            int j = 7;
            for (; j >= 0; --j) { tot += hist[t * 8 + j]; if (tot >= NMS_TOPK_) break; }
            if (j < 0) j = 0;
            cut = t * 8 + j;
        }
        s_cut = cut;
    }
    __syncthreads();
    unsigned int cutoff = (unsigned int)s_cut;

    // Pass 2: collect candidates at/above cutoff bin
    for (int i = tid; i < N_ANCH / 4; i += 256) {
        float4 v = sc4[i];
        float vv[4] = {v.x, v.y, v.z, v.w};
#pragma unroll
        for (int k = 0; k < 4; ++k) {
            if (vv[k] > SCORE_THR_) {
                unsigned int bits = __float_as_uint(vv[k]);
                if (score_bin(bits) >= cutoff) {
                    unsigned int pos = atomicAdd(&s_cnt, 1u);
                    if (pos < CAPB) {
                        sel[pos] = ((unsigned long long)bits << 32) |
                                   (unsigned long long)(~(unsigned int)(i * 4 + k));
                    }
                }
            }
        }
    }
    __syncthreads();

    unsigned int M = s_cnt;
    if (M > CAPB) M = CAPB;
    unsigned int P2 = 1;
    while (P2 < M) P2 <<= 1;
    if (P2 < 2) P2 = 2;
    for (unsigned int k = M + tid; k < P2; k += 256) sel[k] = 0ull;
    __syncthreads();

    // Barrier-free bitonic sort: wave 0 only (wave64 lockstep), desc order
    if (wave == 0) {
        for (unsigned int k = 2; k <= P2; k <<= 1) {
            for (unsigned int j = k >> 1; j > 0; j >>= 1) {
                for (unsigned int t = (unsigned int)lane; t < P2; t += 64) {
                    unsigned int ixj = t ^ j;
                    if (ixj > t) {
                        unsigned long long a0 = sel[t], b0 = sel[ixj];
                        bool desc = ((t & k) == 0);
                        if (desc ? (a0 < b0) : (a0 > b0)) { sel[t] = b0; sel[ixj] = a0; }
                    }
                }
                __threadfence_block();  // order LDS rounds within the wave
            }
        }
    }
    __syncthreads();

    unsigned int K = M < NMS_TOPK_ ? M : NMS_TOPK_;
    if (tid < (int)K) {
        unsigned long long kk = sel[tid];
        unsigned int idx = ~((unsigned int)(kk & 0xFFFFFFFFull));
        const float* bp = boxes + ((size_t)b * N_ANCH + idx) * 4;
        bx[tid][0] = bp[0]; bx[tid][1] = bp[1];
        bx[tid][2] = bp[2]; bx[tid][3] = bp[3];
        bx[tid][4] = __uint_as_float((unsigned int)(kk >> 32));
    }
    __syncthreads();

    // Wave-synchronous greedy NMS + compaction: wave 0, zero barriers.
    if (wave == 0) {
        bool k0 = (unsigned int)lane < K;
        bool k1 = (unsigned int)(64 + lane) < K;
        float x00 = 0, y00 = 0, x01 = 0, y01 = 0, a0 = 0, sv0 = 0;
        float x10 = 0, y10 = 0, x11 = 0, y11 = 0, a1 = 0, sv1 = 0;
        if (k0) {
            x00 = bx[lane][0]; y00 = bx[lane][1];
            x01 = bx[lane][2]; y01 = bx[lane][3]; sv0 = bx[lane][4];
            a0 = (x01 - x00) * (y01 - y00);
        }
        if (k1) {
            x10 = bx[64 + lane][0]; y10 = bx[64 + lane][1];
            x11 = bx[64 + lane][2]; y11 = bx[64 + lane][3]; sv1 = bx[64 + lane][4];
            a1 = (x11 - x10) * (y11 - y10);
        }
        unsigned long long km0 = __ballot(k0);
        unsigned long long km1 = __ballot(k1);
        for (unsigned int i = 0; i < K; ++i) {
            bool ki = ((((i < 64) ? km0 : km1) >> (i & 63)) & 1ull) != 0ull;
            if (ki) {
                float rx0 = bx[i][0], ry0 = bx[i][1], rx1 = bx[i][2], ry1 = bx[i][3];
                float ra = (rx1 - rx0) * (ry1 - ry0);
                if (k0 && (unsigned int)lane > i) {
                    float lx = fmaxf(rx0, x00), ly = fmaxf(ry0, y00);
                    float rx = fminf(rx1, x01), ry = fminf(ry1, y01);
                    float w = fmaxf(rx - lx, 0.f), h = fmaxf(ry - ly, 0.f);
                    float inter = w * h;
                    float iou = inter / (ra + a0 - inter + 1e-9f);
                    if (iou > IOU_THR_) k0 = false;
                }
                if (k1 && (unsigned int)(64 + lane) > i) {
                    float lx = fmaxf(rx0, x10), ly = fmaxf(ry0, y10);
                    float rx = fminf(rx1, x11), ry = fminf(ry1, y11);
                    float w = fmaxf(rx - lx, 0.f), h = fmaxf(ry - ly, 0.f);
                    float inter = w * h;
                    float iou = inter / (ra + a1 - inter + 1e-9f);
                    if (iou > IOU_THR_) k1 = false;
                }
                km0 = __ballot(k0);
                km1 = __ballot(k1);
            }
        }
        // Parallel compaction straight from registers
        float* scd = cls_score + ((size_t)b * NUM_CLASSES + c) * MAX_OUT_;
        float* bod = cls_box + ((size_t)b * NUM_CLASSES + c) * (MAX_OUT_ * 4);
        int n0 = __popcll(km0);
        int n = n0 + __popcll(km1);
        if (k0) {
            int pos = __popcll(km0 & ((1ull << lane) - 1ull));
            if (pos < MAX_OUT_) {
                scd[pos] = sv0;
                bod[pos * 4 + 0] = x00; bod[pos * 4 + 1] = y00;
                bod[pos * 4 + 2] = x01; bod[pos * 4 + 3] = y01;
            }
        }
        if (k1) {
            int pos = n0 + __popcll(km1 & ((1ull << lane) - 1ull));
            if (pos < MAX_OUT_) {
                scd[pos] = sv1;
                bod[pos * 4 + 0] = x10; bod[pos * 4 + 1] = y10;
                bod[pos * 4 + 2] = x11; bod[pos * 4 + 3] = y11;
            }
        }
        int start = n < MAX_OUT_ ? n : MAX_OUT_;
        for (int p2 = start + lane; p2 < MAX_OUT_; p2 += 64) {
            scd[p2] = -1.0f;
            bod[p2 * 4 + 0] = 0.f; bod[p2 * 4 + 1] = 0.f;
            bod[p2 * 4 + 2] = 0.f; bod[p2 * 4 + 3] = 0.f;
        }
    }
}

// ---- F3: per-image final top-100 via histogram cutoff ----
__global__ void __launch_bounds__(256) final_fast_kernel(
    const float* __restrict__ cls_score, const float* __restrict__ cls_box,
    float* __restrict__ out) {
    int b = blockIdx.x;
    int tid = threadIdx.x;
    const int NC = NUM_CLASSES * MAX_OUT_;  // 8000
    const float* sc = cls_score + (size_t)b * NC;

    __shared__ unsigned int hist[NBINS];
    __shared__ unsigned int segsum[256];
    __shared__ unsigned long long keys[CAPC];
    __shared__ unsigned int s_cnt, s_tot;
    __shared__ int s_cut;

    for (int k = tid; k < NBINS; k += 256) hist[k] = 0u;
    if (tid == 0) s_cnt = 0u;
    __syncthreads();

    for (int k = tid; k < NC; k += 256) {
        float s = sc[k];
        if (s > 0.0f) atomicAdd(&hist[score_bin(__float_as_uint(s))], 1u);
    }
    __syncthreads();

    unsigned int ss = 0;
    for (int k = 0; k < 8; ++k) ss += hist[tid * 8 + k];
    segsum[tid] = ss;
    __syncthreads();
    if (tid == 0) {
        unsigned int total = 0;
        for (int t = 0; t < 256; ++t) total += segsum[t];
        s_tot = total;
        unsigned int tot = 0; int cut = 0; int t = 255;
        for (; t >= 0; --t) {
            if (tot + segsum[t] >= MAX_OUT_) break;
            tot += segsum[t];
        }
        if (t >= 0) {
            int j = 7;
            for (; j >= 0; --j) { tot += hist[t * 8 + j]; if (tot >= MAX_OUT_) break; }
            if (j < 0) j = 0;
            cut = t * 8 + j;
        }
        s_cut = cut;
    }
    __syncthreads();
    unsigned int cutoff = (unsigned int)s_cut;

    for (int k = tid; k < NC; k += 256) {
        float s = sc[k];
        if (s > 0.0f && score_bin(__float_as_uint(s)) >= cutoff) {
            unsigned int pos = atomicAdd(&s_cnt, 1u);
            if (pos < CAPC) {
                keys[pos] = ((unsigned long long)__float_as_uint(s) << 32) |
                            (unsigned long long)(~(unsigned int)k);
            }
        }
    }
    __syncthreads();

    unsigned int M = s_cnt;
    if (M > CAPC) M = CAPC;
    unsigned int P2 = 1;
    while (P2 < M) P2 <<= 1;
    if (P2 < 2) P2 = 2;
    for (unsigned int k = M + tid; k < P2; k += 256) keys[k] = 0ull;
    __syncthreads();

    if (tid < 64) {
        for (unsigned int k = 2; k <= P2; k <<= 1) {
            for (unsigned int j = k >> 1; j > 0; j >>= 1) {
                for (unsigned int t = (unsigned int)tid; t < P2; t += 64) {
                    unsigned int ixj = t ^ j;
                    if (ixj > t) {
                        unsigned long long a0 = keys[t], b0 = keys[ixj];
                        bool desc = ((t & k) == 0);
                        if (desc ? (a0 < b0) : (a0 > b0)) { keys[t] = b0; keys[ixj] = a0; }
                    }
                }
                __threadfence_block();
            }
        }
    }
    __syncthreads();

    float* ob = out;                              // boxes  16*100*4
    float* os = out + B_IMG * MAX_OUT_ * 4;       // scores 16*100
    float* oc = os + B_IMG * MAX_OUT_;            // cls    16*100
    float* on = oc + B_IMG * MAX_OUT_;            // n_valid 16

    unsigned int K = M < MAX_OUT_ ? M : MAX_OUT_;
    if (tid < MAX_OUT_) {
        if ((unsigned int)tid < K) {
            unsigned long long kk = keys[tid];
            unsigned int flat = ~((unsigned int)(kk & 0xFFFFFFFFull));
            float sv = __uint_as_float((unsigned int)(kk >> 32));
            const float* bp = cls_box + ((size_t)b * NC + flat) * 4;
            os[b * MAX_OUT_ + tid] = sv;
            oc[b * MAX_OUT_ + tid] = (float)(flat / MAX_OUT_);
            ob[(b * MAX_OUT_ + tid) * 4 + 0] = bp[0];
            ob[(b * MAX_OUT_ + tid) * 4 + 1] = bp[1];
            ob[(b * MAX_OUT_ + tid) * 4 + 2] = bp[2];
            ob[(b * MAX_OUT_ + tid) * 4 + 3] = bp[3];
        } else {
            os[b * MAX_OUT_ + tid] = 0.0f;
            oc[b * MAX_OUT_ + tid] = 0.0f;
            ob[(b * MAX_OUT_ + tid) * 4 + 0] = 0.0f;
            ob[(b * MAX_OUT_ + tid) * 4 + 1] = 0.0f;
            ob[(b * MAX_OUT_ + tid) * 4 + 2] = 0.0f;
            ob[(b * MAX_OUT_ + tid) * 4 + 3] = 0.0f;
        }
    }
    if (tid == 0) {
        unsigned int nv = s_tot < MAX_OUT_ ? s_tot : MAX_OUT_;
        on[b] = (float)nv;
    }
}

// ============================================================================
// FALLBACK PATH (round-1, known-correct) — used when ws_size is too small
// ============================================================================

__global__ void __launch_bounds__(256) decode_kernel(
    const float* __restrict__ p3, const float* __restrict__ p4,
    const float* __restrict__ p5, float* __restrict__ boxes,
    float* __restrict__ obj) {
    int gid = blockIdx.x * blockDim.x + threadIdx.x;
    if (gid >= B_IMG * N_ANCH) return;
    int b = gid / N_ANCH;
    int i = gid - b * N_ANCH;
    const float* p; int W, il, lvl; float stride;
    if (i < 19200)      { p = p3; W = 80; il = i;         lvl = 0; stride = 8.f;  }
    else if (i < 24000) { p = p4; W = 40; il = i - 19200; lvl = 1; stride = 16.f; }
    else                { p = p5; W = 20; il = i - 24000; lvl = 2; stride = 32.f; }
    int y = il / (W * 3);
    int t = il - y * W * 3;
    int x = t / 3;
    int a = t - x * 3;
    const float* q = p + ((((size_t)b * W + y) * W + x) * 255 + a * 85);
    float cx = (sigmoidf_(q[0]) + (float)x) * stride;
    float cy = (sigmoidf_(q[1]) + (float)y) * stride;
    float bw = expf(q[2]) * c_anch[lvl * 3 + a][0];
    float bh = expf(q[3]) * c_anch[lvl * 3 + a][1];
    float* bo = boxes + (size_t)gid * 4;
    bo[0] = cx - bw * 0.5f; bo[1] = cy - bh * 0.5f;
    bo[2] = cx + bw * 0.5f; bo[3] = cy + bh * 0.5f;
    obj[gid] = sigmoidf_(q[4]);
}

__device__ __forceinline__ float cand_score(
    const float* __restrict__ p3, const float* __restrict__ p4,
    const float* __restrict__ p5, const float* __restrict__ obj,
    int b, int c, int i) {
    const float* p; int W, il;
    if (i < 19200)      { p = p3; W = 80; il = i;         }
    else if (i < 24000) { p = p4; W = 40; il = i - 19200; }
    else                { p = p5; W = 20; il = i - 24000; }
    int y = il / (W * 3);
    int t = il - y * W * 3;
    int x = t / 3;
    int a = t - x * 3;
    float cl = p[(((size_t)b * W + y) * W + x) * 255 + a * 85 + 5 + c];
    return obj[b * N_ANCH + i] * sigmoidf_(cl);
}

__global__ void __launch_bounds__(256) topk_nms_kernel(
    const float* __restrict__ p3, const float* __restrict__ p4,
    const float* __restrict__ p5, const float* __restrict__ boxes,
    const float* __restrict__ obj, float* __restrict__ cls_score,
    float* __restrict__ cls_box) {
    int b = blockIdx.x / NUM_CLASSES;
    int c = blockIdx.x % NUM_CLASSES;
    int tid = threadIdx.x;

    __shared__ unsigned int hist[NBINS];
    __shared__ unsigned long long keys[CAP];
    __shared__ unsigned int s_cnt, s_cutoff;
    __shared__ float bx[NMS_TOPK_][5];
    __shared__ float bs[NMS_TOPK_];
    __shared__ int keep[NMS_TOPK_];

    for (int k = tid; k < NBINS; k += 256) hist[k] = 0u;
    if (tid == 0) s_cnt = 0u;
    __syncthreads();

    for (int i = tid; i < N_ANCH; i += 256) {
        float s = cand_score(p3, p4, p5, obj, b, c, i);
        if (s > SCORE_THR_) atomicAdd(&hist[score_bin(__float_as_uint(s))], 1u);
    }
    __syncthreads();

    if (tid == 0) {
        unsigned int total = 0;
        int cut = 0;
        for (int k = NBINS - 1; k >= 0; --k) {
            total += hist[k];
            if (total >= NMS_TOPK_) { cut = k; break; }
        }
        s_cutoff = (unsigned int)cut;
    }
    __syncthreads();
    unsigned int cutoff = s_cutoff;

    for (int i = tid; i < N_ANCH; i += 256) {
        float s = cand_score(p3, p4, p5, obj, b, c, i);
        if (s > SCORE_THR_) {
            unsigned int bits = __float_as_uint(s);
            if (score_bin(bits) >= cutoff) {
                unsigned int pos = atomicAdd(&s_cnt, 1u);
                if (pos < CAP) {
                    keys[pos] = ((unsigned long long)bits << 32) |
                                (unsigned long long)(~(unsigned int)i);
                }
            }
        }
    }
    __syncthreads();

    unsigned int M = s_cnt;
    if (M > CAP) M = CAP;
    unsigned int P2 = 1;
    while (P2 < M) P2 <<= 1;
    if (P2 < 2) P2 = 2;
    for (unsigned int k = M + tid; k < P2; k += 256) keys[k] = 0ull;
    __syncthreads();

    for (unsigned int k = 2; k <= P2; k <<= 1) {
        for (unsigned int j = k >> 1; j > 0; j >>= 1) {
            for (unsigned int t = tid; t < P2; t += 256) {
                unsigned int ixj = t ^ j;
                if (ixj > t) {
                    unsigned long long a0 = keys[t], b0 = keys[ixj];
                    bool desc = ((t & k) == 0);
                    if (desc ? (a0 < b0) : (a0 > b0)) { keys[t] = b0; keys[ixj] = a0; }
                }
            }
            __syncthreads();
        }
    }

    unsigned int K = M < NMS_TOPK_ ? M : NMS_TOPK_;
    if (tid < (int)K) {
        unsigned long long kk = keys[tid];
        unsigned int idx = ~((unsigned int)(kk & 0xFFFFFFFFull));
        const float* bp = boxes + ((size_t)b * N_ANCH + idx) * 4;
        bx[tid][0] = bp[0]; bx[tid][1] = bp[1];
        bx[tid][2] = bp[2]; bx[tid][3] = bp[3];
        bs[tid] = __uint_as_float((unsigned int)(kk >> 32));
        keep[tid] = 1;
    }
    __syncthreads();

    for (unsigned int i = 0; i < K; ++i) {
        if (keep[i]) {
            unsigned int t = (unsigned int)tid;
            if (t > i && t < K && keep[t]) {
                float ax0 = bx[i][0], ay0 = bx[i][1], ax1 = bx[i][2], ay1 = bx[i][3];
                float cx0 = bx[t][0], cy0 = bx[t][1], cx1 = bx[t][2], cy1 = bx[t][3];
                float areaA = (ax1 - ax0) * (ay1 - ay0);
                float areaB = (cx1 - cx0) * (cy1 - cy0);
                float lx = fmaxf(ax0, cx0), ly = fmaxf(ay0, cy0);
                float rx = fminf(ax1, cx1), ry = fminf(ay1, cy1);
                float w = rx - lx; if (w < 0.f) w = 0.f;
                float h = ry - ly; if (h < 0.f) h = 0.f;
                float inter = w * h;
                float iou = inter / (areaA + areaB - inter + 1e-9f);
                if (iou > IOU_THR_) keep[t] = 0;
            }
        }
        __syncthreads();
    }

    if (tid == 0) {
        float* scd = cls_score + ((size_t)b * NUM_CLASSES + c) * MAX_OUT_;
        float* bod = cls_box + ((size_t)b * NUM_CLASSES + c) * MAX_OUT_ * 4;
        int out_n = 0;
        for (unsigned int t2 = 0; t2 < K && out_n < MAX_OUT_; ++t2) {
            if (keep[t2]) {
                scd[out_n] = bs[t2];
                bod[out_n * 4 + 0] = bx[t2][0];
                bod[out_n * 4 + 1] = bx[t2][1];
                bod[out_n * 4 + 2] = bx[t2][2];
                bod[out_n * 4 + 3] = bx[t2][3];
                out_n++;
            }
        }
        for (; out_n < MAX_OUT_; ++out_n) {
            scd[out_n] = -1.0f;
            bod[out_n * 4 + 0] = 0.f; bod[out_n * 4 + 1] = 0.f;
            bod[out_n * 4 + 2] = 0.f; bod[out_n * 4 + 3] = 0.f;
        }
    }
}

extern "C" void kernel_launch(void* const* d_in, const int* in_sizes, int n_in,
                              void* d_out, int out_size, void* d_ws, size_t ws_size,
                              hipStream_t stream) {
    const float* p3 = (const float*)d_in[0];
    const float* p4 = (const float*)d_in[1];
    const float* p5 = (const float*)d_in[2];

    const size_t score_t_elems = (size_t)B_IMG * NUM_CLASSES * N_ANCH;
    const size_t boxes_elems   = (size_t)B_IMG * N_ANCH * 4;
    const size_t clsS_elems    = (size_t)B_IMG * NUM_CLASSES * MAX_OUT_;
    const size_t clsB_elems    = clsS_elems * 4;
    const size_t need_fast = (score_t_elems + boxes_elems + clsS_elems + clsB_elems) * sizeof(float);

    float* ws = (float*)d_ws;

    if (ws_size >= need_fast) {
        float* score_t   = ws;
        float* boxes     = score_t + score_t_elems;
        float* cls_score = boxes + boxes_elems;
        float* cls_box   = cls_score + clsS_elems;

        decode_scores_kernel<<<B_IMG * 315, 256, 0, stream>>>(p3, p4, p5, boxes, score_t);
        topk_nms_fast_kernel<<<B_IMG * NUM_CLASSES, 256, 0, stream>>>(
            score_t, boxes, cls_score, cls_box);
        final_fast_kernel<<<B_IMG, 256, 0, stream>>>(cls_score, cls_box, (float*)d_out);
    } else {
        float* boxes = ws;
        float* obj = boxes + boxes_elems;
        float* cls_score = obj + (size_t)B_IMG * N_ANCH;
        float* cls_box = cls_score + clsS_elems;

        int tot = B_IMG * N_ANCH;
        decode_kernel<<<(tot + 255) / 256, 256, 0, stream>>>(p3, p4, p5, boxes, obj);
        topk_nms_kernel<<<B_IMG * NUM_CLASSES, 256, 0, stream>>>(
            p3, p4, p5, boxes, obj, cls_score, cls_box);
        final_fast_kernel<<<B_IMG, 256, 0, stream>>>(cls_score, cls_box, (float*)d_out);
    }
}